// Round 11
// baseline (249.662 us; speedup 1.0000x reference)
//
#include <hip/hip_runtime.h>
#include <hip/hip_bf16.h>
#include <cstdint>

typedef __attribute__((ext_vector_type(8))) short bf16x8;
typedef __attribute__((ext_vector_type(4))) short short4v;
typedef __attribute__((ext_vector_type(4))) float f32x4;

#define MFMA(a, b, c) __builtin_amdgcn_mfma_f32_16x16x32_bf16((a), (b), (c), 0, 0, 0)

__device__ __forceinline__ unsigned short f2bf(float f) {  // RNE
  union { float f; unsigned int u; } v;
  v.f = f;
  unsigned int r = v.u + 0x7FFFu + ((v.u >> 16) & 1u);
  return (unsigned short)(r >> 16);
}

// packed f32x2 -> bf16x2 (RNE), single instruction
__device__ __forceinline__ unsigned int cvtpk(float lo, float hi) {
  unsigned int r;
  asm("v_cvt_pk_bf16_f32 %0, %1, %2" : "=v"(r) : "v"(lo), "v"(hi));
  return r;
}

// async 16B global -> LDS (wave-uniform LDS base + lane*16)
__device__ __forceinline__ void async_cp16(const unsigned short* g, unsigned short* l) {
  __builtin_amdgcn_global_load_lds(
      (const __attribute__((address_space(1))) unsigned int*)g,
      (__attribute__((address_space(3))) unsigned int*)l, 16, 0, 0);
}

// Fused preprocessing (one launch instead of three). Blocks [0,4096): x
// fp32->bf16. [4096,4864): transpose+cvt w_attn. [4864,5120): w_proj.
__global__ __launch_bounds__(256) void prep(const float* __restrict__ x,
                                            const float* __restrict__ w_attn,
                                            const float* __restrict__ w_proj,
                                            unsigned short* __restrict__ xb,
                                            unsigned short* __restrict__ wT,
                                            unsigned short* __restrict__ wpT) {
  int bid = blockIdx.x;
  if (bid < 4096) {  // cvt_x
    size_t i = ((size_t)bid * 256 + threadIdx.x) * 8;
    float4 a = *(const float4*)(x + i);
    float4 b = *(const float4*)(x + i + 4);
    bf16x8 p;
    p[0] = (short)f2bf(a.x); p[1] = (short)f2bf(a.y);
    p[2] = (short)f2bf(a.z); p[3] = (short)f2bf(a.w);
    p[4] = (short)f2bf(b.x); p[5] = (short)f2bf(b.y);
    p[6] = (short)f2bf(b.z); p[7] = (short)f2bf(b.w);
    *(bf16x8*)(xb + i) = p;
    return;
  }
  const float* in;
  unsigned short* out;
  int N, j;
  if (bid < 4864) {
    j = bid - 4096;  // 768 blocks = 16 x 48
    in = w_attn; out = wT; N = 3072;
  } else {
    j = bid - 4864;  // 256 blocks = 16 x 16
    in = w_proj; out = wpT; N = 1024;
  }
  const int K = 1024;
  int k0 = (j & 15) * 64;
  int n0 = (j >> 4) * 64;
  __shared__ float tile[64][65];
  int c = threadIdx.x & 63;
  int rb = threadIdx.x >> 6;
#pragma unroll
  for (int i = 0; i < 16; ++i) {
    int r = rb * 16 + i;
    tile[r][c] = in[(size_t)(k0 + r) * N + (n0 + c)];
  }
  __syncthreads();
#pragma unroll
  for (int i = 0; i < 16; ++i) {
    int r = rb * 16 + i;
    out[(size_t)(n0 + r) * K + (k0 + c)] = f2bf(tile[c][r]);
  }
}

// QKV GEMM: X (8192x1024 bf16) @ WT^T (3072x1024 bf16 [n][k]).
// BK=64, XOR-swizzled LDS (source-permuted so global_load_lds stays linear).
// (2-phase 128x128 proven structure.)
__global__ __launch_bounds__(256) void gemm_qkv(const unsigned short* __restrict__ X,
                                                const unsigned short* __restrict__ WT,
                                                unsigned short* __restrict__ qb,
                                                unsigned short* __restrict__ kb,
                                                unsigned short* __restrict__ vt) {
  const int K = 1024;
  __shared__ unsigned short As[128 * 64];
  __shared__ unsigned short Bs[128 * 64];
  int t = threadIdx.x, lane = t & 63, w = t >> 6;
  int quad = lane >> 4, l15 = lane & 15;
  int sl7 = l15 & 7;
  int wm = (w >> 1) * 64, wn = (w & 1) * 64;
  int row0 = blockIdx.y * 128, col0 = blockIdx.x * 128;
  int srow = w * 8 + (lane >> 3);           // rows (+i*32)
  int schunk = (lane & 7) ^ (lane >> 3);    // source chunk (swizzle)
  const unsigned short* aSrc = X + (size_t)(row0 + srow) * K + schunk * 8;
  const unsigned short* bSrc = WT + (size_t)(col0 + srow) * K + schunk * 8;
  unsigned short* ldsA = &As[(w * 8) * 64];
  unsigned short* ldsB = &Bs[(w * 8) * 64];
  f32x4 zero4 = {0.f, 0.f, 0.f, 0.f};
  f32x4 acc[4][4];
#pragma unroll
  for (int i = 0; i < 4; ++i)
#pragma unroll
    for (int j = 0; j < 4; ++j) acc[i][j] = zero4;

  for (int k0 = 0; k0 < K; k0 += 64) {
    __syncthreads();
#pragma unroll
    for (int i = 0; i < 4; ++i)
      async_cp16(aSrc + (size_t)i * 32 * K + k0, ldsA + i * 32 * 64);
#pragma unroll
    for (int i = 0; i < 4; ++i)
      async_cp16(bSrc + (size_t)i * 32 * K + k0, ldsB + i * 32 * 64);
    __syncthreads();
#pragma unroll
    for (int h = 0; h < 2; ++h) {
      bf16x8 af[4], bfr[4];
#pragma unroll
      for (int mt = 0; mt < 4; ++mt)
        af[mt] = *(const bf16x8*)&As[(wm + mt * 16 + l15) * 64 +
                                     ((h * 4 + quad) ^ sl7) * 8];
#pragma unroll
      for (int nt = 0; nt < 4; ++nt)
        bfr[nt] = *(const bf16x8*)&Bs[(wn + nt * 16 + l15) * 64 +
                                      ((h * 4 + quad) ^ sl7) * 8];
#pragma unroll
      for (int mt = 0; mt < 4; ++mt)
#pragma unroll
        for (int nt = 0; nt < 4; ++nt)
          acc[mt][nt] = MFMA(af[mt], bfr[nt], acc[mt][nt]);
    }
  }

  const float qscale = 0.125f * 1.4426950408889634f;  // folded into Q
#pragma unroll
  for (int mt = 0; mt < 4; ++mt) {
    int rix0 = row0 + wm + mt * 16 + quad * 4;
    int b = rix0 >> 11;
    int s0 = rix0 & 2047;
#pragma unroll
    for (int nt = 0; nt < 4; ++nt) {
      int c = col0 + wn + nt * 16 + l15;
      int which = c >> 10;  // 0=Q 1=K 2=V (uniform across lanes)
      int e = c & 1023;
      int h = e >> 6, d = e & 63;
      size_t bh = (size_t)b * 16 + h;
      if (which == 2) {
        short4v pv;
#pragma unroll
        for (int r = 0; r < 4; ++r) pv[r] = (short)f2bf(acc[mt][nt][r]);
        *(short4v*)(vt + (bh * 64 + d) * 2048 + s0) = pv;
      } else {
        unsigned short* dst = (which == 0) ? qb : kb;
        float sc = (which == 0) ? qscale : 1.0f;
#pragma unroll
        for (int r = 0; r < 4; ++r)
          dst[(bh * 2048 + (s0 + r)) * 64 + d] = f2bf(acc[mt][nt][r] * sc);
      }
    }
  }
}

// Flash attention v14: v11 body and layouts, but KVBLK=128 — K DMA stages
// 128 rows per barrier (Ks[2][128x64] = 32KB, still 2 blocks/CU) and the
// two 64-chunk computes run back-to-back BETWEEN barriers: halves the
// barrier/vmcnt-drain count (34 -> 17/block) and lets chunk1's ds_read/QK
// interleave with chunk0's exp2/PV (ILP instead of barrier serialization).
// V register rotation, swizzles, guards, numerics identical to v11.
// (Occupancy pushes R1/R2/R8/R9 all failed via spill — body needs ~150
// VGPR; 2 waves/SIMD is the operating point. Do not re-attempt.)
__global__ __launch_bounds__(256, 2) void flash_attn(const unsigned short* __restrict__ qb,
                                                     const unsigned short* __restrict__ kb,
                                                     const unsigned short* __restrict__ vt,
                                                     unsigned short* __restrict__ yb) {
  __shared__ unsigned short Ks[2][128 * 64];
  int idx = blockIdx.x;
  int p = idx >> 6;                     // pair index 0..7 -> q-tiles {15-p, p}
  int sub = idx & 63;
  int bh = (sub & 7) * 8 + (sub >> 3);  // XCD (idx&7) -> bh chunk of 8
  int t = threadIdx.x, lane = t & 63, w = t >> 6;
  int quad = lane >> 4, l15 = lane & 15;
  f32x4 zero4 = {0.f, 0.f, 0.f, 0.f};
  bf16x8 ones;
#pragma unroll
  for (int i = 0; i < 8; ++i) ones[i] = (short)0x3F80;  // bf16 1.0
  int b = bh >> 4, h = bh & 15;

  int srow_st = t >> 3;  // 0..31; rows +32k share row-bits {0,1,3} -> same swz
  int swz_st = (srow_st & 3) | (((srow_st >> 3) & 1) << 2);
  int sslot = (t & 7) ^ swz_st;
  const unsigned short* kp0 =
      kb + ((size_t)bh * 2048 + srow_st) * 64 + sslot * 8;
  const unsigned short* Vb = vt + (size_t)bh * (64 * 2048);
  int fbase = (l15 >> 2) * 8 + (l15 & 3);
  int rslot0 = (quad ^ (l15 & 7)) * 8;
  int rslot1 = ((quad ^ 4) ^ (l15 & 7)) * 8;

  for (int seg = 0; seg < 2; ++seg) {
    int qt = seg ? p : (15 - p);
    int qrow0 = qt * 128 + w * 32;
    int ktmax = 2 * qt + 1;  // last 64-chunk index (odd -> chunks pair evenly)

    bf16x8 aq0[2], aq1[2];
#pragma unroll
    for (int s = 0; s < 2; ++s) {
      const unsigned short* Qp =
          qb + ((size_t)bh * 2048 + qrow0 + s * 16 + l15) * 64 + quad * 8;
      aq0[s] = *(const bf16x8*)Qp;
      aq1[s] = *(const bf16x8*)(Qp + 32);
    }
    f32x4 o[2][4], accl[2];
#pragma unroll
    for (int s = 0; s < 2; ++s) {
      accl[s] = zero4;
#pragma unroll
      for (int nt = 0; nt < 4; ++nt) o[s][nt] = zero4;
    }

    __syncthreads();  // prior seg's Ks readers done
    // prologue: DMA k-rows [0,128) into buf 0
#pragma unroll
    for (int i = 0; i < 4; ++i)
      async_cp16(kp0 + (size_t)(32 * i) * 64, &Ks[0][i * 2048 + t * 8]);
    int cur = 0;

    bf16x8 vA0[4], vA1[4], vB0[4], vB1[4];

#define LOADV(KB, v0, v1)                                                     \
  do {                                                                        \
    _Pragma("unroll") for (int nt = 0; nt < 4; ++nt) {                        \
      const unsigned short* Vp =                                              \
          Vb + (size_t)(nt * 16 + l15) * 2048 + (KB) + quad * 8;              \
      (v0)[nt] = *(const bf16x8*)Vp;                                          \
      (v1)[nt] = *(const bf16x8*)(Vp + 32);                                   \
    }                                                                         \
  } while (0)

// OFF = LDS half offset (0 for chunk0, 4096 for chunk1 of the 128-row tile)
#define COMPUTE(KB, OFF, v0, v1)                                              \
  do {                                                                        \
    int kbase = (KB);                                                         \
    const unsigned short* Kc = &Ks[cur][OFF];                                 \
    bf16x8 kf0[4], kf1[4];                                                    \
    _Pragma("unroll") for (int nt = 0; nt < 4; ++nt) {                        \
      int row = fbase + (nt & 1) * 4 + (nt >> 1) * 32;                        \
      kf0[nt] = *(const bf16x8*)&Kc[row * 64 + rslot0];                       \
      kf1[nt] = *(const bf16x8*)&Kc[row * 64 + rslot1];                       \
    }                                                                         \
    _Pragma("unroll") for (int s = 0; s < 2; ++s) {                           \
      int rowb = qrow0 + s * 16;                                              \
      if (kbase <= rowb + 15) { /* wave-uniform */                            \
        f32x4 pv4[4];                                                         \
        _Pragma("unroll") for (int nt = 0; nt < 4; ++nt) {                    \
          f32x4 z = zero4;                                                    \
          z = MFMA(kf0[nt], aq0[s], z);                                       \
          z = MFMA(kf1[nt], aq1[s], z);                                       \
          pv4[nt] = z;                                                        \
        }                                                                     \
        if (kbase + 63 > rowb) { /* diagonal: mask k > q */                   \
          int qg = rowb + l15;                                                \
          _Pragma("unroll") for (int nt = 0; nt < 4; ++nt) {                  \
            int colb = kbase + quad * 8 + (nt & 1) * 4 + ((nt >> 1) << 5);    \
            _Pragma("unroll") for (int r = 0; r < 4; ++r)                     \
              if (colb + r > qg) pv4[nt][r] = -1e30f;                         \
          }                                                                   \
        }                                                                     \
        _Pragma("unroll") for (int nt = 0; nt < 4; ++nt)                      \
          _Pragma("unroll") for (int r = 0; r < 4; ++r)                       \
            pv4[nt][r] = __builtin_amdgcn_exp2f(pv4[nt][r]);                  \
        union { unsigned int u[4]; bf16x8 v; } A0, A1;                        \
        A0.u[0] = cvtpk(pv4[0][0], pv4[0][1]);                                \
        A0.u[1] = cvtpk(pv4[0][2], pv4[0][3]);                                \
        A0.u[2] = cvtpk(pv4[1][0], pv4[1][1]);                                \
        A0.u[3] = cvtpk(pv4[1][2], pv4[1][3]);                                \
        A1.u[0] = cvtpk(pv4[2][0], pv4[2][1]);                                \
        A1.u[1] = cvtpk(pv4[2][2], pv4[2][3]);                                \
        A1.u[2] = cvtpk(pv4[3][0], pv4[3][1]);                                \
        A1.u[3] = cvtpk(pv4[3][2], pv4[3][3]);                                \
        bf16x8 ap0 = A0.v, ap1 = A1.v;                                        \
        accl[s] = MFMA(ap0, ones, accl[s]);                                   \
        accl[s] = MFMA(ap1, ones, accl[s]);                                   \
        _Pragma("unroll") for (int nt = 0; nt < 4; ++nt) {                    \
          o[s][nt] = MFMA(ap0, (v0)[nt], o[s][nt]);                           \
          o[s][nt] = MFMA(ap1, (v1)[nt], o[s][nt]);                           \
        }                                                                     \
      }                                                                       \
    }                                                                         \
  } while (0)

    LOADV(0, vA0, vA1);
    for (int kt = 0; kt <= ktmax; kt += 2) {
      int kb0 = kt * 64;
      __syncthreads();  // drains DMA(->buf cur) + V loads; buf cur^1 free
      if (kt + 2 <= ktmax) {  // DMA next 128-row tile into other buffer
        const unsigned short* nk = kp0 + (size_t)(kb0 + 128) * 64;
#pragma unroll
        for (int i = 0; i < 4; ++i)
          async_cp16(nk + (size_t)(32 * i) * 64, &Ks[cur ^ 1][i * 2048 + t * 8]);
      }
      // chunk 0 of this tile
      if (kb0 + 64 <= qrow0 + 31) LOADV(kb0 + 64, vB0, vB1);
      if (kb0 <= qrow0 + 31) COMPUTE(kb0, 0, vA0, vA1);
      // chunk 1 of this tile (no barrier between — ILP across chunks)
      if (kt + 2 <= ktmax && kb0 + 128 <= qrow0 + 31) LOADV(kb0 + 128, vA0, vA1);
      if (kb0 + 64 <= qrow0 + 31) COMPUTE(kb0 + 64, 4096, vB0, vB1);
      cur ^= 1;
    }
#undef COMPUTE
#undef LOADV

    // epilogue for this segment
#pragma unroll
    for (int s = 0; s < 2; ++s) {
      float inv[4];
#pragma unroll
      for (int r = 0; r < 4; ++r) inv[r] = 1.0f / accl[s][r];
#pragma unroll
      for (int nt = 0; nt < 4; ++nt) {
        int e = h * 64 + nt * 16 + l15;
#pragma unroll
        for (int r = 0; r < 4; ++r) {
          int srow_g = qrow0 + s * 16 + quad * 4 + r;
          yb[((size_t)b * 2048 + srow_g) * 1024 + e] = f2bf(o[s][nt][r] * inv[r]);
        }
      }
    }
  }
}

// Output projection: Y (8192x1024 bf16) @ WT^T -> fp32 out. Same BK=64 swizzle.
__global__ __launch_bounds__(256) void gemm_proj(const unsigned short* __restrict__ Y,
                                                 const unsigned short* __restrict__ WT,
                                                 float* __restrict__ out) {
  const int K = 1024;
  __shared__ unsigned short As[128 * 64];
  __shared__ unsigned short Bs[128 * 64];
  int t = threadIdx.x, lane = t & 63, w = t >> 6;
  int quad = lane >> 4, l15 = lane & 15;
  int sl7 = l15 & 7;
  int wm = (w >> 1) * 64, wn = (w & 1) * 64;
  int row0 = blockIdx.y * 128, col0 = blockIdx.x * 128;
  int srow = w * 8 + (lane >> 3);
  int schunk = (lane & 7) ^ (lane >> 3);
  const unsigned short* aSrc = Y + (size_t)(row0 + srow) * K + schunk * 8;
  const unsigned short* bSrc = WT + (size_t)(col0 + srow) * K + schunk * 8;
  unsigned short* ldsA = &As[(w * 8) * 64];
  unsigned short* ldsB = &Bs[(w * 8) * 64];
  f32x4 zero4 = {0.f, 0.f, 0.f, 0.f};
  f32x4 acc[4][4];
#pragma unroll
  for (int i = 0; i < 4; ++i)
#pragma unroll
    for (int j = 0; j < 4; ++j) acc[i][j] = zero4;

  for (int k0 = 0; k0 < K; k0 += 64) {
    __syncthreads();
#pragma unroll
    for (int i = 0; i < 4; ++i)
      async_cp16(aSrc + (size_t)i * 32 * K + k0, ldsA + i * 32 * 64);
#pragma unroll
    for (int i = 0; i < 4; ++i)
      async_cp16(bSrc + (size_t)i * 32 * K + k0, ldsB + i * 32 * 64);
    __syncthreads();
#pragma unroll
    for (int h = 0; h < 2; ++h) {
      bf16x8 af[4], bfr[4];
#pragma unroll
      for (int mt = 0; mt < 4; ++mt)
        af[mt] = *(const bf16x8*)&As[(wm + mt * 16 + l15) * 64 +
                                     ((h * 4 + quad) ^ sl7) * 8];
#pragma unroll
      for (int nt = 0; nt < 4; ++nt)
        bfr[nt] = *(const bf16x8*)&Bs[(wn + nt * 16 + l15) * 64 +
                                      ((h * 4 + quad) ^ sl7) * 8];
#pragma unroll
      for (int mt = 0; mt < 4; ++mt)
#pragma unroll
        for (int nt = 0; nt < 4; ++nt)
          acc[mt][nt] = MFMA(af[mt], bfr[nt], acc[mt][nt]);
    }
  }

#pragma unroll
  for (int mt = 0; mt < 4; ++mt) {
    int rix0 = row0 + wm + mt * 16 + quad * 4;
#pragma unroll
    for (int nt = 0; nt < 4; ++nt) {
      int c = col0 + wn + nt * 16 + l15;
#pragma unroll
      for (int r = 0; r < 4; ++r)
        out[(size_t)(rix0 + r) * 1024 + c] = acc[mt][nt][r];
    }
  }
}

extern "C" void kernel_launch(void* const* d_in, const int* in_sizes, int n_in,
                              void* d_out, int out_size, void* d_ws, size_t ws_size,
                              hipStream_t stream) {
  const float* x = (const float*)d_in[0];       // (4, 2048, 1024) fp32
  const float* w_attn = (const float*)d_in[1];  // (1024, 3072) fp32
  const float* w_proj = (const float*)d_in[2];  // (1024, 1024) fp32
  float* out = (float*)d_out;                   // (4, 2048, 1024) fp32
  char* ws = (char*)d_ws;
  unsigned short* wT  = (unsigned short*)(ws + 0);         // (3072,1024) bf16
  unsigned short* wpT = (unsigned short*)(ws + 6291456);   // (1024,1024) bf16
  unsigned short* qb  = (unsigned short*)(ws + 8388608);   // (b,h,s,d) pre-scaled
  unsigned short* kb  = (unsigned short*)(ws + 25165824);  // (b,h,s,d)
  unsigned short* vt  = (unsigned short*)(ws + 41943040);  // (b,h,d,s)
  unsigned short* xyb = (unsigned short*)(ws + 58720256);  // xb then yb

  prep<<<5120, 256, 0, stream>>>(x, w_attn, w_proj, xyb, wT, wpT);
  gemm_qkv<<<dim3(24, 64), 256, 0, stream>>>(xyb, wT, qb, kb, vt);
  flash_attn<<<dim3(512), 256, 0, stream>>>(qb, kb, vt, xyb);
  gemm_proj<<<dim3(8, 64), 256, 0, stream>>>(xyb, wpT, out);
}

// Round 12
// 242.744 us; speedup vs baseline: 1.0285x; 1.0285x over previous
//
#include <hip/hip_runtime.h>
#include <hip/hip_bf16.h>
#include <cstdint>

typedef __attribute__((ext_vector_type(8))) short bf16x8;
typedef __attribute__((ext_vector_type(4))) short short4v;
typedef __attribute__((ext_vector_type(4))) float f32x4;

#define MFMA(a, b, c) __builtin_amdgcn_mfma_f32_16x16x32_bf16((a), (b), (c), 0, 0, 0)

__device__ __forceinline__ unsigned short f2bf(float f) {  // RNE
  union { float f; unsigned int u; } v;
  v.f = f;
  unsigned int r = v.u + 0x7FFFu + ((v.u >> 16) & 1u);
  return (unsigned short)(r >> 16);
}

// packed f32x2 -> bf16x2 (RNE), single instruction
__device__ __forceinline__ unsigned int cvtpk(float lo, float hi) {
  unsigned int r;
  asm("v_cvt_pk_bf16_f32 %0, %1, %2" : "=v"(r) : "v"(lo), "v"(hi));
  return r;
}

// async 16B global -> LDS (wave-uniform LDS base + lane*16)
__device__ __forceinline__ void async_cp16(const unsigned short* g, unsigned short* l) {
  __builtin_amdgcn_global_load_lds(
      (const __attribute__((address_space(1))) unsigned int*)g,
      (__attribute__((address_space(3))) unsigned int*)l, 16, 0, 0);
}

// Fused preprocessing (one launch instead of three). Blocks [0,4096): x
// fp32->bf16. [4096,4864): transpose+cvt w_attn. [4864,5120): w_proj.
__global__ __launch_bounds__(256) void prep(const float* __restrict__ x,
                                            const float* __restrict__ w_attn,
                                            const float* __restrict__ w_proj,
                                            unsigned short* __restrict__ xb,
                                            unsigned short* __restrict__ wT,
                                            unsigned short* __restrict__ wpT) {
  int bid = blockIdx.x;
  if (bid < 4096) {  // cvt_x
    size_t i = ((size_t)bid * 256 + threadIdx.x) * 8;
    float4 a = *(const float4*)(x + i);
    float4 b = *(const float4*)(x + i + 4);
    bf16x8 p;
    p[0] = (short)f2bf(a.x); p[1] = (short)f2bf(a.y);
    p[2] = (short)f2bf(a.z); p[3] = (short)f2bf(a.w);
    p[4] = (short)f2bf(b.x); p[5] = (short)f2bf(b.y);
    p[6] = (short)f2bf(b.z); p[7] = (short)f2bf(b.w);
    *(bf16x8*)(xb + i) = p;
    return;
  }
  const float* in;
  unsigned short* out;
  int N, j;
  if (bid < 4864) {
    j = bid - 4096;  // 768 blocks = 16 x 48
    in = w_attn; out = wT; N = 3072;
  } else {
    j = bid - 4864;  // 256 blocks = 16 x 16
    in = w_proj; out = wpT; N = 1024;
  }
  const int K = 1024;
  int k0 = (j & 15) * 64;
  int n0 = (j >> 4) * 64;
  __shared__ float tile[64][65];
  int c = threadIdx.x & 63;
  int rb = threadIdx.x >> 6;
#pragma unroll
  for (int i = 0; i < 16; ++i) {
    int r = rb * 16 + i;
    tile[r][c] = in[(size_t)(k0 + r) * N + (n0 + c)];
  }
  __syncthreads();
#pragma unroll
  for (int i = 0; i < 16; ++i) {
    int r = rb * 16 + i;
    out[(size_t)(n0 + r) * K + (k0 + c)] = f2bf(tile[c][r]);
  }
}

// QKV GEMM v3: 2-phase DOUBLE-BUFFERED (T3 minimum form). Old loop was
// sync -> issue DMA -> sync -> compute: staging latency 100% exposed
// between the two barriers (m233's 607 TF signature — matched our counters).
// Now: issue DMA(t+1 -> buf^1) FIRST, compute t from buf, ONE barrier
// (its vmcnt drain covered by the compute). Barriers 32 -> 16 per block.
// LDS 64KB (2 buf) -> still 2 blocks/CU. Numerics bit-identical.
__global__ __launch_bounds__(256) void gemm_qkv(const unsigned short* __restrict__ X,
                                                const unsigned short* __restrict__ WT,
                                                unsigned short* __restrict__ qb,
                                                unsigned short* __restrict__ kb,
                                                unsigned short* __restrict__ vt) {
  const int K = 1024;
  __shared__ unsigned short As[2][128 * 64];
  __shared__ unsigned short Bs[2][128 * 64];
  int t = threadIdx.x, lane = t & 63, w = t >> 6;
  int quad = lane >> 4, l15 = lane & 15;
  int sl7 = l15 & 7;
  int wm = (w >> 1) * 64, wn = (w & 1) * 64;
  int row0 = blockIdx.y * 128, col0 = blockIdx.x * 128;
  int srow = w * 8 + (lane >> 3);           // rows (+i*32)
  int schunk = (lane & 7) ^ (lane >> 3);    // source chunk (swizzle)
  const unsigned short* aSrc = X + (size_t)(row0 + srow) * K + schunk * 8;
  const unsigned short* bSrc = WT + (size_t)(col0 + srow) * K + schunk * 8;
  f32x4 zero4 = {0.f, 0.f, 0.f, 0.f};
  f32x4 acc[4][4];
#pragma unroll
  for (int i = 0; i < 4; ++i)
#pragma unroll
    for (int j = 0; j < 4; ++j) acc[i][j] = zero4;

#define STAGE(S, K0)                                                  \
  do {                                                                \
    _Pragma("unroll") for (int i = 0; i < 4; ++i)                     \
      async_cp16(aSrc + (size_t)i * 32 * K + (K0),                    \
                 &As[S][(w * 8) * 64 + i * 32 * 64]);                 \
    _Pragma("unroll") for (int i = 0; i < 4; ++i)                     \
      async_cp16(bSrc + (size_t)i * 32 * K + (K0),                    \
                 &Bs[S][(w * 8) * 64 + i * 32 * 64]);                 \
  } while (0)

  STAGE(0, 0);
  __syncthreads();  // tile 0 landed
  int cur = 0;
  for (int k0 = 0; k0 < K; k0 += 64) {
    if (k0 + 64 < K) STAGE(cur ^ 1, k0 + 64);  // issue next tile first
#pragma unroll
    for (int h = 0; h < 2; ++h) {
      bf16x8 af[4], bfr[4];
#pragma unroll
      for (int mt = 0; mt < 4; ++mt)
        af[mt] = *(const bf16x8*)&As[cur][(wm + mt * 16 + l15) * 64 +
                                         ((h * 4 + quad) ^ sl7) * 8];
#pragma unroll
      for (int nt = 0; nt < 4; ++nt)
        bfr[nt] = *(const bf16x8*)&Bs[cur][(wn + nt * 16 + l15) * 64 +
                                          ((h * 4 + quad) ^ sl7) * 8];
#pragma unroll
      for (int mt = 0; mt < 4; ++mt)
#pragma unroll
        for (int nt = 0; nt < 4; ++nt)
          acc[mt][nt] = MFMA(af[mt], bfr[nt], acc[mt][nt]);
    }
    __syncthreads();  // drains next-tile DMAs (covered by compute) + readers
    cur ^= 1;
  }
#undef STAGE

  const float qscale = 0.125f * 1.4426950408889634f;  // folded into Q
#pragma unroll
  for (int mt = 0; mt < 4; ++mt) {
    int rix0 = row0 + wm + mt * 16 + quad * 4;
    int b = rix0 >> 11;
    int s0 = rix0 & 2047;
#pragma unroll
    for (int nt = 0; nt < 4; ++nt) {
      int c = col0 + wn + nt * 16 + l15;
      int which = c >> 10;  // 0=Q 1=K 2=V (uniform across lanes)
      int e = c & 1023;
      int h = e >> 6, d = e & 63;
      size_t bh = (size_t)b * 16 + h;
      if (which == 2) {
        short4v pv;
#pragma unroll
        for (int r = 0; r < 4; ++r) pv[r] = (short)f2bf(acc[mt][nt][r]);
        *(short4v*)(vt + (bh * 64 + d) * 2048 + s0) = pv;
      } else {
        unsigned short* dst = (which == 0) ? qb : kb;
        float sc = (which == 0) ? qscale : 1.0f;
#pragma unroll
        for (int r = 0; r < 4; ++r)
          dst[(bh * 2048 + (s0 + r)) * 64 + d] = f2bf(acc[mt][nt][r] * sc);
      }
    }
  }
}

// Flash attention v11 (best measured, restored): in-register P via swapped
// QK^T, single-barrier dbuf K DMA, register double-buffer for V, grid 512
// paired q-tiles {15-p, p} (uniform 34 iters), XCD-clustered bh, 2 blocks/CU.
// Falsified levers — do not re-attempt: occupancy (R1/R2/R8/R9: spill),
// barrier-count/KVBLK=128 (R11: neutral), direct-K (R3: regressed).
__global__ __launch_bounds__(256, 2) void flash_attn(const unsigned short* __restrict__ qb,
                                                     const unsigned short* __restrict__ kb,
                                                     const unsigned short* __restrict__ vt,
                                                     unsigned short* __restrict__ yb) {
  __shared__ unsigned short Ks[2][64 * 64];
  int idx = blockIdx.x;
  int p = idx >> 6;                     // pair index 0..7 -> q-tiles {15-p, p}
  int sub = idx & 63;
  int bh = (sub & 7) * 8 + (sub >> 3);  // XCD (idx&7) -> bh chunk of 8
  int t = threadIdx.x, lane = t & 63, w = t >> 6;
  int quad = lane >> 4, l15 = lane & 15;
  f32x4 zero4 = {0.f, 0.f, 0.f, 0.f};
  bf16x8 ones;
#pragma unroll
  for (int i = 0; i < 8; ++i) ones[i] = (short)0x3F80;  // bf16 1.0
  int b = bh >> 4, h = bh & 15;

  int srow_st = t >> 3;  // 0..31
  int swz_st = (srow_st & 3) | (((srow_st >> 3) & 1) << 2);
  int sslot = (t & 7) ^ swz_st;
  const unsigned short* kp0 =
      kb + ((size_t)bh * 2048 + srow_st) * 64 + sslot * 8;
  const unsigned short* Vb = vt + (size_t)bh * (64 * 2048);
  int fbase = (l15 >> 2) * 8 + (l15 & 3);
  int rslot0 = (quad ^ (l15 & 7)) * 8;
  int rslot1 = ((quad ^ 4) ^ (l15 & 7)) * 8;

  for (int seg = 0; seg < 2; ++seg) {
    int qt = seg ? p : (15 - p);
    int qrow0 = qt * 128 + w * 32;
    int ktmax = 2 * qt + 1;

    bf16x8 aq0[2], aq1[2];
#pragma unroll
    for (int s = 0; s < 2; ++s) {
      const unsigned short* Qp =
          qb + ((size_t)bh * 2048 + qrow0 + s * 16 + l15) * 64 + quad * 8;
      aq0[s] = *(const bf16x8*)Qp;
      aq1[s] = *(const bf16x8*)(Qp + 32);
    }
    f32x4 o[2][4], accl[2];
#pragma unroll
    for (int s = 0; s < 2; ++s) {
      accl[s] = zero4;
#pragma unroll
      for (int nt = 0; nt < 4; ++nt) o[s][nt] = zero4;
    }

    __syncthreads();  // prior seg's Ks readers done
    async_cp16(kp0, &Ks[0][t * 8]);
    async_cp16(kp0 + 32 * 64, &Ks[0][2048 + t * 8]);
    int cur = 0;

    bf16x8 vA0[4], vA1[4], vB0[4], vB1[4];

#define LOADV(KB, v0, v1)                                                     \
  do {                                                                        \
    _Pragma("unroll") for (int nt = 0; nt < 4; ++nt) {                        \
      const unsigned short* Vp =                                              \
          Vb + (size_t)(nt * 16 + l15) * 2048 + (KB) + quad * 8;              \
      (v0)[nt] = *(const bf16x8*)Vp;                                          \
      (v1)[nt] = *(const bf16x8*)(Vp + 32);                                   \
    }                                                                         \
  } while (0)

#define COMPUTE(KB, v0, v1)                                                   \
  do {                                                                        \
    int kbase = (KB);                                                         \
    const unsigned short* Kc = &Ks[cur][0];                                   \
    bf16x8 kf0[4], kf1[4];                                                    \
    _Pragma("unroll") for (int nt = 0; nt < 4; ++nt) {                        \
      int row = fbase + (nt & 1) * 4 + (nt >> 1) * 32;                        \
      kf0[nt] = *(const bf16x8*)&Kc[row * 64 + rslot0];                       \
      kf1[nt] = *(const bf16x8*)&Kc[row * 64 + rslot1];                       \
    }                                                                         \
    _Pragma("unroll") for (int s = 0; s < 2; ++s) {                           \
      int rowb = qrow0 + s * 16;                                              \
      if (kbase <= rowb + 15) { /* wave-uniform */                            \
        f32x4 pv4[4];                                                         \
        _Pragma("unroll") for (int nt = 0; nt < 4; ++nt) {                    \
          f32x4 z = zero4;                                                    \
          z = MFMA(kf0[nt], aq0[s], z);                                       \
          z = MFMA(kf1[nt], aq1[s], z);                                       \
          pv4[nt] = z;                                                        \
        }                                                                     \
        if (kbase + 63 > rowb) { /* diagonal: mask k > q */                   \
          int qg = rowb + l15;                                                \
          _Pragma("unroll") for (int nt = 0; nt < 4; ++nt) {                  \
            int colb = kbase + quad * 8 + (nt & 1) * 4 + ((nt >> 1) << 5);    \
            _Pragma("unroll") for (int r = 0; r < 4; ++r)                     \
              if (colb + r > qg) pv4[nt][r] = -1e30f;                         \
          }                                                                   \
        }                                                                     \
        _Pragma("unroll") for (int nt = 0; nt < 4; ++nt)                      \
          _Pragma("unroll") for (int r = 0; r < 4; ++r)                       \
            pv4[nt][r] = __builtin_amdgcn_exp2f(pv4[nt][r]);                  \
        union { unsigned int u[4]; bf16x8 v; } A0, A1;                        \
        A0.u[0] = cvtpk(pv4[0][0], pv4[0][1]);                                \
        A0.u[1] = cvtpk(pv4[0][2], pv4[0][3]);                                \
        A0.u[2] = cvtpk(pv4[1][0], pv4[1][1]);                                \
        A0.u[3] = cvtpk(pv4[1][2], pv4[1][3]);                                \
        A1.u[0] = cvtpk(pv4[2][0], pv4[2][1]);                                \
        A1.u[1] = cvtpk(pv4[2][2], pv4[2][3]);                                \
        A1.u[2] = cvtpk(pv4[3][0], pv4[3][1]);                                \
        A1.u[3] = cvtpk(pv4[3][2], pv4[3][3]);                                \
        bf16x8 ap0 = A0.v, ap1 = A1.v;                                        \
        accl[s] = MFMA(ap0, ones, accl[s]);                                   \
        accl[s] = MFMA(ap1, ones, accl[s]);                                   \
        _Pragma("unroll") for (int nt = 0; nt < 4; ++nt) {                    \
          o[s][nt] = MFMA(ap0, (v0)[nt], o[s][nt]);                           \
          o[s][nt] = MFMA(ap1, (v1)[nt], o[s][nt]);                           \
        }                                                                     \
      }                                                                       \
    }                                                                         \
  } while (0)

#define ITER(KT, cv0, cv1, nv0, nv1)                                          \
  do {                                                                        \
    int kb0 = (KT) * 64;                                                      \
    __syncthreads(); /* drains DMA(kt->buf cur); buf cur^1 readers done */    \
    if ((KT) < ktmax) {                                                       \
      const unsigned short* nk = kp0 + (size_t)(kb0 + 64) * 64;               \
      async_cp16(nk, &Ks[cur ^ 1][t * 8]);                                    \
      async_cp16(nk + 32 * 64, &Ks[cur ^ 1][2048 + t * 8]);                   \
    }                                                                         \
    if ((KT) + 1 <= ktmax && kb0 + 64 <= qrow0 + 31) LOADV(kb0 + 64, nv0, nv1); \
    if (kb0 <= qrow0 + 31) COMPUTE(kb0, cv0, cv1);                            \
    cur ^= 1;                                                                 \
  } while (0)

    LOADV(0, vA0, vA1);
    for (int kt = 0; kt <= ktmax; kt += 2) {
      ITER(kt, vA0, vA1, vB0, vB1);
      if (kt + 1 > ktmax) break;
      ITER(kt + 1, vB0, vB1, vA0, vA1);
    }
#undef ITER
#undef COMPUTE
#undef LOADV

    // epilogue for this segment
#pragma unroll
    for (int s = 0; s < 2; ++s) {
      float inv[4];
#pragma unroll
      for (int r = 0; r < 4; ++r) inv[r] = 1.0f / accl[s][r];
#pragma unroll
      for (int nt = 0; nt < 4; ++nt) {
        int e = h * 64 + nt * 16 + l15;
#pragma unroll
        for (int r = 0; r < 4; ++r) {
          int srow_g = qrow0 + s * 16 + quad * 4 + r;
          yb[((size_t)b * 2048 + srow_g) * 1024 + e] = f2bf(o[s][nt][r] * inv[r]);
        }
      }
    }
  }
}

// Output projection v2: 2-phase double-buffered (same T3 change as qkv).
__global__ __launch_bounds__(256) void gemm_proj(const unsigned short* __restrict__ Y,
                                                 const unsigned short* __restrict__ WT,
                                                 float* __restrict__ out) {
  const int K = 1024;
  __shared__ unsigned short As[2][128 * 64];
  __shared__ unsigned short Bs[2][128 * 64];
  int t = threadIdx.x, lane = t & 63, w = t >> 6;
  int quad = lane >> 4, l15 = lane & 15;
  int sl7 = l15 & 7;
  int wm = (w >> 1) * 64, wn = (w & 1) * 64;
  int row0 = blockIdx.y * 128, col0 = blockIdx.x * 128;
  int srow = w * 8 + (lane >> 3);
  int schunk = (lane & 7) ^ (lane >> 3);
  const unsigned short* aSrc = Y + (size_t)(row0 + srow) * K + schunk * 8;
  const unsigned short* bSrc = WT + (size_t)(col0 + srow) * K + schunk * 8;
  f32x4 zero4 = {0.f, 0.f, 0.f, 0.f};
  f32x4 acc[4][4];
#pragma unroll
  for (int i = 0; i < 4; ++i)
#pragma unroll
    for (int j = 0; j < 4; ++j) acc[i][j] = zero4;

#define STAGE(S, K0)                                                  \
  do {                                                                \
    _Pragma("unroll") for (int i = 0; i < 4; ++i)                     \
      async_cp16(aSrc + (size_t)i * 32 * K + (K0),                    \
                 &As[S][(w * 8) * 64 + i * 32 * 64]);                 \
    _Pragma("unroll") for (int i = 0; i < 4; ++i)                     \
      async_cp16(bSrc + (size_t)i * 32 * K + (K0),                    \
                 &Bs[S][(w * 8) * 64 + i * 32 * 64]);                 \
  } while (0)

  STAGE(0, 0);
  __syncthreads();
  int cur = 0;
  for (int k0 = 0; k0 < K; k0 += 64) {
    if (k0 + 64 < K) STAGE(cur ^ 1, k0 + 64);
#pragma unroll
    for (int h = 0; h < 2; ++h) {
      bf16x8 af[4], bfr[4];
#pragma unroll
      for (int mt = 0; mt < 4; ++mt)
        af[mt] = *(const bf16x8*)&As[cur][(wm + mt * 16 + l15) * 64 +
                                         ((h * 4 + quad) ^ sl7) * 8];
#pragma unroll
      for (int nt = 0; nt < 4; ++nt)
        bfr[nt] = *(const bf16x8*)&Bs[cur][(wn + nt * 16 + l15) * 64 +
                                          ((h * 4 + quad) ^ sl7) * 8];
#pragma unroll
      for (int mt = 0; mt < 4; ++mt)
#pragma unroll
        for (int nt = 0; nt < 4; ++nt)
          acc[mt][nt] = MFMA(af[mt], bfr[nt], acc[mt][nt]);
    }
    __syncthreads();
    cur ^= 1;
  }
#undef STAGE

#pragma unroll
  for (int mt = 0; mt < 4; ++mt) {
    int rix0 = row0 + wm + mt * 16 + quad * 4;
#pragma unroll
    for (int nt = 0; nt < 4; ++nt) {
      int c = col0 + wn + nt * 16 + l15;
#pragma unroll
      for (int r = 0; r < 4; ++r)
        out[(size_t)(rix0 + r) * 1024 + c] = acc[mt][nt][r];
    }
  }
}

extern "C" void kernel_launch(void* const* d_in, const int* in_sizes, int n_in,
                              void* d_out, int out_size, void* d_ws, size_t ws_size,
                              hipStream_t stream) {
  const float* x = (const float*)d_in[0];       // (4, 2048, 1024) fp32
  const float* w_attn = (const float*)d_in[1];  // (1024, 3072) fp32
  const float* w_proj = (const float*)d_in[2];  // (1024, 1024) fp32
  float* out = (float*)d_out;                   // (4, 2048, 1024) fp32
  char* ws = (char*)d_ws;
  unsigned short* wT  = (unsigned short*)(ws + 0);         // (3072,1024) bf16
  unsigned short* wpT = (unsigned short*)(ws + 6291456);   // (1024,1024) bf16
  unsigned short* qb  = (unsigned short*)(ws + 8388608);   // (b,h,s,d) pre-scaled
  unsigned short* kb  = (unsigned short*)(ws + 25165824);  // (b,h,s,d)
  unsigned short* vt  = (unsigned short*)(ws + 41943040);  // (b,h,d,s)
  unsigned short* xyb = (unsigned short*)(ws + 58720256);  // xb then yb

  prep<<<5120, 256, 0, stream>>>(x, w_attn, w_proj, xyb, wT, wpT);
  gemm_qkv<<<dim3(24, 64), 256, 0, stream>>>(xyb, wT, qb, kb, vt);
  flash_attn<<<dim3(512), 256, 0, stream>>>(qb, kb, vt, xyb);
  gemm_proj<<<dim3(8, 64), 256, 0, stream>>>(xyb, wpT, out);
}